// Round 3
// baseline (582.526 us; speedup 1.0000x reference)
//
#include <hip/hip_runtime.h>

#define NN 50000      // nodes
#define NE 800000     // edges
#define ND 128        // node_attr_dim
#define ED 16         // edge_attr_dim
#define HID 300       // hidden
#define KP1 192       // padded K for gemm1 (128+16 -> 192)
#define KP2 320       // padded K for gemm2 (300 -> 320)
#define NP 320        // padded N (300 -> 320)

#define SCAN_T 256
#define SCAN_B ((NN + SCAN_T - 1) / SCAN_T)   // 196 blocks

typedef __attribute__((ext_vector_type(8))) short short8;
typedef __attribute__((ext_vector_type(4))) float f32x4;

__device__ __forceinline__ unsigned short f2b(float f) {
    unsigned int u = __float_as_uint(f);
    u = (u + 0x7FFFu + ((u >> 16) & 1u)) >> 16;   // RNE
    return (unsigned short)u;
}
__device__ __forceinline__ float blo(unsigned int u) {
    return __uint_as_float(u << 16);
}
__device__ __forceinline__ float bhi(unsigned int u) {
    return __uint_as_float(u & 0xffff0000u);
}

// in-block inclusive scan of v across 256 threads (4 waves)
__device__ __forceinline__ int block_iscan(int v, int tid) {
    int lane = tid & 63;
    #pragma unroll
    for (int off = 1; off < 64; off <<= 1) {
        int t = __shfl_up(v, off);
        if (lane >= off) v += t;
    }
    __shared__ int wsum[4];
    int wid = tid >> 6;
    if (lane == 63) wsum[wid] = v;
    __syncthreads();
    int add = 0;
    #pragma unroll
    for (int w = 0; w < 4; ++w)
        if (w < wid) add += wsum[w];
    return v + add;
}

// ---------------------------------------------------------------- CSR build
__global__ void hist_kernel(const int* __restrict__ ei, int* __restrict__ rowptr) {
    int e = blockIdx.x * blockDim.x + threadIdx.x;
    if (e < NE) atomicAdd(&rowptr[ei[NE + e] + 1], 1);
}

// phase 1: local inclusive scan of rowptr[1..NN], block totals out
__global__ __launch_bounds__(SCAN_T) void scan1(int* __restrict__ rowptr,
                                                int* __restrict__ blockSums) {
    int i = blockIdx.x * SCAN_T + threadIdx.x;
    int v = (i < NN) ? rowptr[1 + i] : 0;
    v = block_iscan(v, threadIdx.x);
    if (i < NN) rowptr[1 + i] = v;
    if (threadIdx.x == SCAN_T - 1) blockSums[blockIdx.x] = v;
}

// phase 2: exclusive scan of block totals (196 <= 256, one block)
__global__ __launch_bounds__(SCAN_T) void scan2(int* __restrict__ blockSums) {
    int t = threadIdx.x;
    int orig = (t < SCAN_B) ? blockSums[t] : 0;
    int v = block_iscan(orig, t);
    if (t < SCAN_B) blockSums[t] = v - orig;   // exclusive
}

// phase 3: add block offsets; emit cursor[] (exclusive prefix per node)
__global__ __launch_bounds__(SCAN_T) void scan3(int* __restrict__ rowptr,
                                                const int* __restrict__ blockSums,
                                                int* __restrict__ cursor) {
    int i = blockIdx.x * SCAN_T + threadIdx.x;
    if (i < NN) {
        int v = rowptr[1 + i] + blockSums[blockIdx.x];
        rowptr[1 + i] = v;
        if (i + 1 < NN) cursor[i + 1] = v;
    }
    if (i == 0) cursor[0] = 0;
}

// packed CSR payloads: csr_sw = {src, w_bits}, csr_ew = {eid, w_bits}
__global__ void fill_kernel(const int* __restrict__ ei, const float* __restrict__ ew,
                            int* __restrict__ cursor, uint2* __restrict__ csr_sw,
                            uint2* __restrict__ csr_ew) {
    int e = blockIdx.x * blockDim.x + threadIdx.x;
    if (e < NE) {
        int d = ei[NE + e];
        int pos = atomicAdd(&cursor[d], 1);
        unsigned int wb = __float_as_uint(ew[e]);
        uint2 sw; sw.x = (unsigned int)ei[e]; sw.y = wb;
        uint2 ee; ee.x = (unsigned int)e;     ee.y = wb;
        csr_sw[pos] = sw;
        csr_ew[pos] = ee;
    }
}

// ------------------- cast x (fp32) -> A1 cols 0..127 (bf16), coalesced -----
__global__ __launch_bounds__(256) void cast_x(const float* __restrict__ x,
                                              unsigned short* __restrict__ A1) {
    int tid = blockIdx.x * blockDim.x + threadIdx.x;   // NN*32 threads
    if (tid >= NN * 32) return;
    int n = tid >> 5, q = tid & 31;
    float4 v = *(const float4*)&x[(size_t)n * ND + q * 4];
    unsigned short o[4] = {f2b(v.x), f2b(v.y), f2b(v.z), f2b(v.w)};
    *(uint2*)&A1[(size_t)n * KP1 + q * 4] = *(uint2*)o;
}

// ---- inc: wave per node; lanes = 4 edge-groups x 16 features; shfl reduce --
__global__ __launch_bounds__(256) void inc_kernel(
    const float* __restrict__ edge_attr,
    const int* __restrict__ rowptr,
    const uint2* __restrict__ csr_ew,
    unsigned short* __restrict__ A1) {
    int n = (blockIdx.x * blockDim.x + threadIdx.x) >> 6;
    int lane = threadIdx.x & 63;
    if (n >= NN) return;
    int g = lane >> 4, j = lane & 15;
    int lo = rowptr[n], hi = rowptr[n + 1];
    float v = 0.f;
    for (int k = lo + g; k < hi; k += 4) {
        uint2 ewp = csr_ew[k];
        float w = __uint_as_float(ewp.y);
        v += w * edge_attr[(size_t)ewp.x * ED + j];
    }
    v += __shfl_xor(v, 16);
    v += __shfl_xor(v, 32);
    if (lane < 16)
        A1[(size_t)n * KP1 + ND + lane] = f2b(v);
    else
        A1[(size_t)n * KP1 + ND + lane] = 0;   // pad cols 144..191
}

// B0T[n][k] = bf16(W0[k][n]) padded to [320][192]
__global__ void castB0(const float* __restrict__ W0, unsigned short* __restrict__ B0T) {
    int n = blockIdx.x, k = threadIdx.x;
    float v = (n < HID && k < ND + ED) ? W0[(size_t)k * HID + n] : 0.f;
    B0T[(size_t)n * KP1 + k] = f2b(v);
}

// BT[n][k] = bf16(W[k][n]) padded to [320][320]
__global__ void castB(const float* __restrict__ W, unsigned short* __restrict__ BT) {
    int n = blockIdx.x, k = threadIdx.x;
    float v = (n < HID && k < HID) ? W[(size_t)k * HID + n] : 0.f;
    BT[(size_t)n * KP2 + k] = f2b(v);
}

// ----------------------------------------------------------- MFMA bf16 GEMM
// 128x160 tile, 2x2 waves. LDS-FREE: fragments loaded directly global->VGPR
// (each wave instr gathers 16 x 64B fully-used segments; B is L2-resident,
// A re-reads are L1/L3-served). No barriers, no vmcnt drains -- the K loop
// fully unrolls (6/10 iters) and the compiler pipelines 50-90 independent
// loads. This replaces the 2-phase LDS pipeline whose per-step vmcnt(0)
// drain serialized ~900cyc HBM latency x NT with nothing to overlap.
template <int MODE, int KP>
__global__ __launch_bounds__(256, 3) void gemm_mfma(
    const unsigned short* __restrict__ A,   // [M, KP] bf16 row-major
    const unsigned short* __restrict__ BT,  // [320, KP] bf16 (B transposed)
    const float* __restrict__ bias,         // [300]
    const float* __restrict__ RES,          // MODE1: h0 [M,300] fp32
    float* __restrict__ C,                  // [M,300] fp32
    unsigned short* __restrict__ h0b,       // MODE0: [M,320] bf16
    int M)
{
    const int tid = threadIdx.x;
    const int m0 = blockIdx.x * 128;
    const int n0 = blockIdx.y * 160;
    const int wave = tid >> 6, lane = tid & 63;
    const int wm = wave >> 1, wn = wave & 1;
    const int quad = lane >> 4, lr = lane & 15;
    f32x4 acc[4][5] = {};

    // thread-constant fragment row bases
    const unsigned short* arow[4];
    const unsigned short* brow[5];
    #pragma unroll
    for (int tm = 0; tm < 4; ++tm) {
        int mg = m0 + wm * 64 + tm * 16 + lr;
        if (mg >= M) mg = M - 1;
        arow[tm] = A + (size_t)mg * KP;
    }
    #pragma unroll
    for (int tn = 0; tn < 5; ++tn)
        brow[tn] = BT + (size_t)(n0 + wn * 80 + tn * 16 + lr) * KP;
    const int kc = quad * 8;   // col offset within a 32-wide K chunk

    #pragma unroll
    for (int t = 0; t < KP / 32; ++t) {
        const int k = t * 32 + kc;
        short8 a[4], b[5];
        #pragma unroll
        for (int tm = 0; tm < 4; ++tm)
            a[tm] = *(const short8*)&arow[tm][k];
        #pragma unroll
        for (int tn = 0; tn < 5; ++tn)
            b[tn] = *(const short8*)&brow[tn][k];
        #pragma unroll
        for (int tm = 0; tm < 4; ++tm)
            #pragma unroll
            for (int tn = 0; tn < 5; ++tn)
                acc[tm][tn] = __builtin_amdgcn_mfma_f32_16x16x32_bf16(
                    a[tm], b[tn], acc[tm][tn], 0, 0, 0);
    }

    #pragma unroll
    for (int tm = 0; tm < 4; ++tm) {
        #pragma unroll
        for (int tn = 0; tn < 5; ++tn) {
            int ng = n0 + wn * 80 + tn * 16 + lr;
            #pragma unroll
            for (int r = 0; r < 4; ++r) {
                int mg = m0 + wm * 64 + tm * 16 + quad * 4 + r;
                if (mg < M && ng < HID) {
                    float v = acc[tm][tn][r] + bias[ng];
                    if (MODE == 1) v += RES[(size_t)mg * HID + ng];
                    v = fmaxf(v, 0.f);
                    C[(size_t)mg * HID + ng] = v;
                    if (MODE == 0) h0b[(size_t)mg * NP + ng] = f2b(v);
                }
            }
        }
    }
}

// ---------------- aggB[n] = bf16(mean_k w_k * h0b[src_k]) ------------------
__global__ __launch_bounds__(256) void agg_kernel(
    const unsigned short* __restrict__ h0b,   // [NN, 320] bf16
    const int* __restrict__ rowptr,
    const uint2* __restrict__ csr_sw,
    unsigned short* __restrict__ aggB)        // [NN, 320] bf16, pad cols = 0
{
    int n = (blockIdx.x * blockDim.x + threadIdx.x) >> 6;
    int lane = threadIdx.x & 63;
    if (n >= NN) return;
    int lo = rowptr[n], hi = rowptr[n + 1];
    float acc[8] = {};
    const uint4* h4 = (const uint4*)h0b;      // row stride = 40 uint4
    bool act = lane < 40;
    int k = lo;
    for (; k + 1 < hi; k += 2) {
        uint2 p0 = csr_sw[k], p1 = csr_sw[k + 1];
        int s0 = (int)p0.x, s1 = (int)p1.x;
        float w0 = __uint_as_float(p0.y), w1 = __uint_as_float(p1.y);
        uint4 r0 = {0, 0, 0, 0}, r1 = {0, 0, 0, 0};
        if (act) {
            r0 = h4[(size_t)s0 * 40 + lane];
            r1 = h4[(size_t)s1 * 40 + lane];
        }
        acc[0] += w0 * blo(r0.x); acc[1] += w0 * bhi(r0.x);
        acc[2] += w0 * blo(r0.y); acc[3] += w0 * bhi(r0.y);
        acc[4] += w0 * blo(r0.z); acc[5] += w0 * bhi(r0.z);
        acc[6] += w0 * blo(r0.w); acc[7] += w0 * bhi(r0.w);
        acc[0] += w1 * blo(r1.x); acc[1] += w1 * bhi(r1.x);
        acc[2] += w1 * blo(r1.y); acc[3] += w1 * bhi(r1.y);
        acc[4] += w1 * blo(r1.z); acc[5] += w1 * bhi(r1.z);
        acc[6] += w1 * blo(r1.w); acc[7] += w1 * bhi(r1.w);
    }
    if (k < hi) {
        uint2 p0 = csr_sw[k];
        int s0 = (int)p0.x;
        float w0 = __uint_as_float(p0.y);
        uint4 r0 = {0, 0, 0, 0};
        if (act) r0 = h4[(size_t)s0 * 40 + lane];
        acc[0] += w0 * blo(r0.x); acc[1] += w0 * bhi(r0.x);
        acc[2] += w0 * blo(r0.y); acc[3] += w0 * bhi(r0.y);
        acc[4] += w0 * blo(r0.z); acc[5] += w0 * bhi(r0.z);
        acc[6] += w0 * blo(r0.w); acc[7] += w0 * bhi(r0.w);
    }
    if (act) {
        float invd = 1.f / fmaxf((float)(hi - lo), 1.f);
        int cbase = lane * 8;
        unsigned int o[4];
        #pragma unroll
        for (int i = 0; i < 4; ++i) {
            int c0 = cbase + 2 * i, c1 = c0 + 1;
            unsigned int ulo = (c0 < HID) ? f2b(acc[2 * i] * invd) : 0;
            unsigned int uhi = (c1 < HID) ? f2b(acc[2 * i + 1] * invd) : 0;
            o[i] = ulo | (uhi << 16);
        }
        uint4* a4 = (uint4*)aggB;
        uint4 v; v.x = o[0]; v.y = o[1]; v.z = o[2]; v.w = o[3];
        a4[(size_t)n * 40 + lane] = v;
    }
}

// ---------------------------------------------------------------- launch
extern "C" void kernel_launch(void* const* d_in, const int* in_sizes, int n_in,
                              void* d_out, int out_size, void* d_ws, size_t ws_size,
                              hipStream_t stream) {
    const float* x           = (const float*)d_in[0];
    const float* edge_attr   = (const float*)d_in[1];
    const float* edge_weight = (const float*)d_in[2];
    const float* W0 = (const float*)d_in[4];
    const float* b0 = (const float*)d_in[5];
    const float* W  = (const float*)d_in[6];
    const float* b  = (const float*)d_in[7];
    const int* ei   = (const int*)d_in[8];

    float* out = (float*)d_out;
    float* h  = out;                          // output 0: [NN, HID]
    float* h0 = out + (size_t)NN * HID;       // output 1: [NN, HID]

    char* p = (char*)d_ws;
    auto alloc = [&](size_t bytes) { char* q = p; p += (bytes + 255) & ~(size_t)255; return q; };
    int*   rowptr  = (int*)  alloc((NN + 1) * sizeof(int));
    int*   cursor  = (int*)  alloc(NN * sizeof(int));
    int*   bsums   = (int*)  alloc(SCAN_B * sizeof(int));
    uint2* csr_sw  = (uint2*)alloc((size_t)NE * sizeof(uint2));
    uint2* csr_ew  = (uint2*)alloc((size_t)NE * sizeof(uint2));
    unsigned short* A1   = (unsigned short*)alloc((size_t)NN * KP1 * 2);
    unsigned short* h0b  = (unsigned short*)alloc((size_t)NN * NP * 2);
    unsigned short* aggB = (unsigned short*)alloc((size_t)NN * NP * 2);
    unsigned short* B0T  = (unsigned short*)alloc((size_t)NP * KP1 * 2);
    unsigned short* BT   = (unsigned short*)alloc((size_t)NP * KP2 * 2);

    hipMemsetAsync(rowptr, 0, (NN + 1) * sizeof(int), stream);
    hist_kernel<<<(NE + 255) / 256, 256, 0, stream>>>(ei, rowptr);
    scan1<<<SCAN_B, SCAN_T, 0, stream>>>(rowptr, bsums);
    scan2<<<1, SCAN_T, 0, stream>>>(bsums);
    scan3<<<SCAN_B, SCAN_T, 0, stream>>>(rowptr, bsums, cursor);
    fill_kernel<<<(NE + 255) / 256, 256, 0, stream>>>(ei, edge_weight, cursor,
                                                      csr_sw, csr_ew);
    castB0<<<NP, KP1, 0, stream>>>(W0, B0T);
    castB<<<NP, KP2, 0, stream>>>(W, BT);
    cast_x<<<(NN * 32 + 255) / 256, 256, 0, stream>>>(x, A1);
    inc_kernel<<<(NN + 3) / 4, 256, 0, stream>>>(edge_attr, rowptr, csr_ew, A1);

    dim3 g((NN + 127) / 128, NP / 160);
    gemm_mfma<0, KP1><<<g, 256, 0, stream>>>(A1, B0T, b0, nullptr, h0, h0b, NN);
    agg_kernel<<<(NN + 3) / 4, 256, 0, stream>>>(h0b, rowptr, csr_sw, aggB);
    gemm_mfma<1, KP2><<<g, 256, 0, stream>>>(aggB, BT, b, h0, h, nullptr, NN);
}

// Round 4
// 473.134 us; speedup vs baseline: 1.2312x; 1.2312x over previous
//
#include <hip/hip_runtime.h>

#define NN 50000      // nodes
#define NE 800000     // edges
#define ND 128        // node_attr_dim
#define ED 16         // edge_attr_dim
#define HID 300       // hidden
#define KP1 192       // padded K for gemm1 (128+16 -> 192)
#define KP2 320       // padded K for gemm2 (300 -> 320)
#define NP 320        // padded N (300 -> 320)

#define SCAN_T 256
#define SCAN_B ((NN + SCAN_T - 1) / SCAN_T)   // 196 blocks

typedef __attribute__((ext_vector_type(8))) short short8;
typedef __attribute__((ext_vector_type(4))) float f32x4;

__device__ __forceinline__ unsigned short f2b(float f) {
    unsigned int u = __float_as_uint(f);
    u = (u + 0x7FFFu + ((u >> 16) & 1u)) >> 16;   // RNE
    return (unsigned short)u;
}
__device__ __forceinline__ float blo(unsigned int u) {
    return __uint_as_float(u << 16);
}
__device__ __forceinline__ float bhi(unsigned int u) {
    return __uint_as_float(u & 0xffff0000u);
}

// async global->LDS: 16B per lane, dest = wave-uniform base + lane*16
__device__ __forceinline__ void gload16(const void* g, void* l) {
    __builtin_amdgcn_global_load_lds(
        (const __attribute__((address_space(1))) void*)g,
        (__attribute__((address_space(3))) void*)l, 16, 0, 0);
}

// in-block inclusive scan of v across 256 threads (4 waves)
__device__ __forceinline__ int block_iscan(int v, int tid) {
    int lane = tid & 63;
    #pragma unroll
    for (int off = 1; off < 64; off <<= 1) {
        int t = __shfl_up(v, off);
        if (lane >= off) v += t;
    }
    __shared__ int wsum[4];
    int wid = tid >> 6;
    if (lane == 63) wsum[wid] = v;
    __syncthreads();
    int add = 0;
    #pragma unroll
    for (int w = 0; w < 4; ++w)
        if (w < wid) add += wsum[w];
    return v + add;
}

// ---------------------------------------------------------------- CSR build
__global__ void hist_kernel(const int* __restrict__ ei, int* __restrict__ rowptr) {
    int e = blockIdx.x * blockDim.x + threadIdx.x;
    if (e < NE) atomicAdd(&rowptr[ei[NE + e] + 1], 1);
}

// phase 1: local inclusive scan of rowptr[1..NN], block totals out
__global__ __launch_bounds__(SCAN_T) void scan1(int* __restrict__ rowptr,
                                                int* __restrict__ blockSums) {
    int i = blockIdx.x * SCAN_T + threadIdx.x;
    int v = (i < NN) ? rowptr[1 + i] : 0;
    v = block_iscan(v, threadIdx.x);
    if (i < NN) rowptr[1 + i] = v;
    if (threadIdx.x == SCAN_T - 1) blockSums[blockIdx.x] = v;
}

// phase 2: exclusive scan of block totals (196 <= 256, one block)
__global__ __launch_bounds__(SCAN_T) void scan2(int* __restrict__ blockSums) {
    int t = threadIdx.x;
    int orig = (t < SCAN_B) ? blockSums[t] : 0;
    int v = block_iscan(orig, t);
    if (t < SCAN_B) blockSums[t] = v - orig;   // exclusive
}

// phase 3: add block offsets; emit cursor[] (exclusive prefix per node)
__global__ __launch_bounds__(SCAN_T) void scan3(int* __restrict__ rowptr,
                                                const int* __restrict__ blockSums,
                                                int* __restrict__ cursor) {
    int i = blockIdx.x * SCAN_T + threadIdx.x;
    if (i < NN) {
        int v = rowptr[1 + i] + blockSums[blockIdx.x];
        rowptr[1 + i] = v;
        if (i + 1 < NN) cursor[i + 1] = v;
    }
    if (i == 0) cursor[0] = 0;
}

// packed CSR payloads: csr_sw = {src, w_bits}, csr_ew = {eid, w_bits}
__global__ void fill_kernel(const int* __restrict__ ei, const float* __restrict__ ew,
                            int* __restrict__ cursor, uint2* __restrict__ csr_sw,
                            uint2* __restrict__ csr_ew) {
    int e = blockIdx.x * blockDim.x + threadIdx.x;
    if (e < NE) {
        int d = ei[NE + e];
        int pos = atomicAdd(&cursor[d], 1);
        unsigned int wb = __float_as_uint(ew[e]);
        uint2 sw; sw.x = (unsigned int)ei[e]; sw.y = wb;
        uint2 ee; ee.x = (unsigned int)e;     ee.y = wb;
        csr_sw[pos] = sw;
        csr_ew[pos] = ee;
    }
}

// ------------------- cast x (fp32) -> A1 cols 0..127 (bf16), coalesced -----
__global__ __launch_bounds__(256) void cast_x(const float* __restrict__ x,
                                              unsigned short* __restrict__ A1) {
    int tid = blockIdx.x * blockDim.x + threadIdx.x;   // NN*32 threads
    if (tid >= NN * 32) return;
    int n = tid >> 5, q = tid & 31;
    float4 v = *(const float4*)&x[(size_t)n * ND + q * 4];
    unsigned short o[4] = {f2b(v.x), f2b(v.y), f2b(v.z), f2b(v.w)};
    *(uint2*)&A1[(size_t)n * KP1 + q * 4] = *(uint2*)o;
}

// ---- inc: wave per node; lanes = 4 edge-groups x 16 features; shfl reduce --
__global__ __launch_bounds__(256) void inc_kernel(
    const float* __restrict__ edge_attr,
    const int* __restrict__ rowptr,
    const uint2* __restrict__ csr_ew,
    unsigned short* __restrict__ A1) {
    int n = (blockIdx.x * blockDim.x + threadIdx.x) >> 6;
    int lane = threadIdx.x & 63;
    if (n >= NN) return;
    int g = lane >> 4, j = lane & 15;
    int lo = rowptr[n], hi = rowptr[n + 1];
    float v = 0.f;
    for (int k = lo + g; k < hi; k += 4) {
        uint2 ewp = csr_ew[k];
        float w = __uint_as_float(ewp.y);
        v += w * edge_attr[(size_t)ewp.x * ED + j];
    }
    v += __shfl_xor(v, 16);
    v += __shfl_xor(v, 32);
    if (lane < 16)
        A1[(size_t)n * KP1 + ND + lane] = f2b(v);
    else
        A1[(size_t)n * KP1 + ND + lane] = 0;   // pad cols 144..191
}

// B0T[n][k] = bf16(W0[k][n]) padded to [320][192]
__global__ void castB0(const float* __restrict__ W0, unsigned short* __restrict__ B0T) {
    int n = blockIdx.x, k = threadIdx.x;
    float v = (n < HID && k < ND + ED) ? W0[(size_t)k * HID + n] : 0.f;
    B0T[(size_t)n * KP1 + k] = f2b(v);
}

// BT[n][k] = bf16(W[k][n]) padded to [320][320]
__global__ void castB(const float* __restrict__ W, unsigned short* __restrict__ BT) {
    int n = blockIdx.x, k = threadIdx.x;
    float v = (n < HID && k < HID) ? W[(size_t)k * HID + n] : 0.f;
    BT[(size_t)n * KP2 + k] = f2b(v);
}

// --------------------------------------------- persistent stream-M MFMA GEMM
// One block per CU. B panel staged in LDS ONCE (swizzled); A streamed in
// 32-row tiles, double-buffered via global_load_lds. Whole K-loop per tile
// runs barrier-free; one __syncthreads per tile whose vmcnt(0) drain is
// covered by ~2000cy of compute+epilogue. XOR swizzle both-sides (rule 21):
// linear LDS dest + swizzled global source chunk + swizzled ds_read chunk,
// c' = (c&~7)|((c&7)^(row&7)); row strides are multiples of 128B so the
// unswizzled read would be a 16-way bank conflict.
template <int MODE, int KP, int BN, int WM, int WN, int RPB>
__global__ __launch_bounds__(256) void gemm_stream(
    const unsigned short* __restrict__ A,   // [M, KP] bf16 row-major
    const unsigned short* __restrict__ BT,  // [320, KP] bf16 (B transposed)
    const float* __restrict__ bias,         // [300]
    const float* __restrict__ RES,          // MODE1: h0 [M,300] fp32
    float* __restrict__ C,                  // [M,300] fp32
    unsigned short* __restrict__ h0b,       // MODE0: [M,320] bf16
    int M)
{
    constexpr int CPR = KP / 8;          // 16B chunks per row
    constexpr int ACH = 32 * CPR;        // chunks per A buffer
    constexpr int BCH = BN * CPR;        // chunks in B panel
    constexpr int AM  = 32 / (16 * WM);  // a-frags per wave
    constexpr int BNW = BN / (16 * WN);  // b-frags per wave (=5)
    __shared__ unsigned short Bs[BCH * 8];     // g1:120KB g2:100KB
    __shared__ unsigned short As[2][ACH * 8];  // g1:24KB  g2:40KB

    const int tid = threadIdx.x;
    const int wave = tid >> 6, lane = tid & 63;
    const int wm = wave / WN, wn = wave % WN;
    const int quad = lane >> 4, lr = lane & 15;
    const int n00 = blockIdx.y * BN;
    const int rbase = blockIdx.x * RPB;
    const int rowend = min(rbase + RPB, M);
    const int nt = (rowend - rbase + 31) >> 5;

    // ---- stage B panel once (swizzled source, linear dest)
    #pragma unroll
    for (int rd = 0; rd < BCH / 256; ++rd) {
        int s = rd * 256 + tid;
        int row = s / CPR, c = s - row * CPR;
        int cs = (c & ~7) | ((c & 7) ^ (row & 7));
        gload16(&BT[(size_t)(n00 + row) * KP + cs * 8], &Bs[s * 8]);
    }
    auto stageA = [&](int buf, int mb) {
        #pragma unroll
        for (int rd = 0; rd < ACH / 256; ++rd) {
            int s = rd * 256 + tid;
            int row = s / CPR, c = s - row * CPR;
            int cs = (c & ~7) | ((c & 7) ^ (row & 7));
            int mg = mb + row; if (mg >= M) mg = M - 1;
            gload16(&A[(size_t)mg * KP + cs * 8], &As[buf][s * 8]);
        }
    };
    stageA(0, rbase);

    float bias_r[BNW];
    #pragma unroll
    for (int tn = 0; tn < BNW; ++tn) {
        int ng = n00 + wn * (BNW * 16) + tn * 16 + lr;
        bias_r[tn] = (ng < HID) ? bias[ng] : 0.f;
    }
    __syncthreads();   // drains vmcnt(0): B panel + first A tile resident

    int cur = 0;
    #pragma unroll 1
    for (int t = 0; t < nt; ++t) {
        const int mb = rbase + t * 32;
        if (t + 1 < nt) stageA(cur ^ 1, mb + 32);   // prefetch next tile

        float res_r[AM][BNW][4];
        if (MODE == 1) {   // prefetch residual before compute (latency hidden)
            #pragma unroll
            for (int tm = 0; tm < AM; ++tm)
            #pragma unroll
            for (int tn = 0; tn < BNW; ++tn) {
                int ng = n00 + wn * (BNW * 16) + tn * 16 + lr;
                int ngc = ng < HID ? ng : HID - 1;
                #pragma unroll
                for (int r = 0; r < 4; ++r) {
                    int mg = mb + (wm * AM + tm) * 16 + quad * 4 + r;
                    int mgc = mg < M ? mg : M - 1;
                    res_r[tm][tn][r] = RES[(size_t)mgc * HID + ngc];
                }
            }
        }

        f32x4 acc[AM][BNW] = {};
        const int rm = lr & 7;
        #pragma unroll
        for (int tt = 0; tt < KP / 32; ++tt) {
            int cA = tt * 4 + quad;
            int sw8 = ((cA & ~7) | ((cA & 7) ^ rm)) * 8;
            short8 a[AM], b[BNW];
            #pragma unroll
            for (int tm = 0; tm < AM; ++tm) {
                int ar = (wm * AM + tm) * 16 + lr;
                a[tm] = *(const short8*)&As[cur][ar * KP + sw8];
            }
            #pragma unroll
            for (int tn = 0; tn < BNW; ++tn) {
                int br = wn * (BNW * 16) + tn * 16 + lr;
                b[tn] = *(const short8*)&Bs[br * KP + sw8];
            }
            #pragma unroll
            for (int tm = 0; tm < AM; ++tm)
                #pragma unroll
                for (int tn = 0; tn < BNW; ++tn)
                    acc[tm][tn] = __builtin_amdgcn_mfma_f32_16x16x32_bf16(
                        a[tm], b[tn], acc[tm][tn], 0, 0, 0);
        }

        #pragma unroll
        for (int tm = 0; tm < AM; ++tm)
        #pragma unroll
        for (int tn = 0; tn < BNW; ++tn) {
            int ng = n00 + wn * (BNW * 16) + tn * 16 + lr;
            #pragma unroll
            for (int r = 0; r < 4; ++r) {
                int mg = mb + (wm * AM + tm) * 16 + quad * 4 + r;
                if (mg < rowend && ng < HID) {
                    float v = acc[tm][tn][r] + bias_r[tn];
                    if (MODE == 1) v += res_r[tm][tn][r];
                    v = fmaxf(v, 0.f);
                    C[(size_t)mg * HID + ng] = v;
                    if (MODE == 0) h0b[(size_t)mg * NP + ng] = f2b(v);
                }
            }
        }
        __syncthreads();   // next-tile stage (issued pre-compute) now drained
        cur ^= 1;
    }
}

// ---------------- aggB[n] = bf16(mean_k w_k * h0b[src_k]) ------------------
__global__ __launch_bounds__(256) void agg_kernel(
    const unsigned short* __restrict__ h0b,   // [NN, 320] bf16
    const int* __restrict__ rowptr,
    const uint2* __restrict__ csr_sw,
    unsigned short* __restrict__ aggB)        // [NN, 320] bf16, pad cols = 0
{
    int n = (blockIdx.x * blockDim.x + threadIdx.x) >> 6;
    int lane = threadIdx.x & 63;
    if (n >= NN) return;
    int lo = rowptr[n], hi = rowptr[n + 1];
    float acc[8] = {};
    const uint4* h4 = (const uint4*)h0b;      // row stride = 40 uint4
    bool act = lane < 40;
    int k = lo;
    for (; k + 1 < hi; k += 2) {
        uint2 p0 = csr_sw[k], p1 = csr_sw[k + 1];
        int s0 = (int)p0.x, s1 = (int)p1.x;
        float w0 = __uint_as_float(p0.y), w1 = __uint_as_float(p1.y);
        uint4 r0 = {0, 0, 0, 0}, r1 = {0, 0, 0, 0};
        if (act) {
            r0 = h4[(size_t)s0 * 40 + lane];
            r1 = h4[(size_t)s1 * 40 + lane];
        }
        acc[0] += w0 * blo(r0.x); acc[1] += w0 * bhi(r0.x);
        acc[2] += w0 * blo(r0.y); acc[3] += w0 * bhi(r0.y);
        acc[4] += w0 * blo(r0.z); acc[5] += w0 * bhi(r0.z);
        acc[6] += w0 * blo(r0.w); acc[7] += w0 * bhi(r0.w);
        acc[0] += w1 * blo(r1.x); acc[1] += w1 * bhi(r1.x);
        acc[2] += w1 * blo(r1.y); acc[3] += w1 * bhi(r1.y);
        acc[4] += w1 * blo(r1.z); acc[5] += w1 * bhi(r1.z);
        acc[6] += w1 * blo(r1.w); acc[7] += w1 * bhi(r1.w);
    }
    if (k < hi) {
        uint2 p0 = csr_sw[k];
        int s0 = (int)p0.x;
        float w0 = __uint_as_float(p0.y);
        uint4 r0 = {0, 0, 0, 0};
        if (act) r0 = h4[(size_t)s0 * 40 + lane];
        acc[0] += w0 * blo(r0.x); acc[1] += w0 * bhi(r0.x);
        acc[2] += w0 * blo(r0.y); acc[3] += w0 * bhi(r0.y);
        acc[4] += w0 * blo(r0.z); acc[5] += w0 * bhi(r0.z);
        acc[6] += w0 * blo(r0.w); acc[7] += w0 * bhi(r0.w);
    }
    if (act) {
        float invd = 1.f / fmaxf((float)(hi - lo), 1.f);
        int cbase = lane * 8;
        unsigned int o[4];
        #pragma unroll
        for (int i = 0; i < 4; ++i) {
            int c0 = cbase + 2 * i, c1 = c0 + 1;
            unsigned int ulo = (c0 < HID) ? f2b(acc[2 * i] * invd) : 0;
            unsigned int uhi = (c1 < HID) ? f2b(acc[2 * i + 1] * invd) : 0;
            o[i] = ulo | (uhi << 16);
        }
        uint4* a4 = (uint4*)aggB;
        uint4 v; v.x = o[0]; v.y = o[1]; v.z = o[2]; v.w = o[3];
        a4[(size_t)n * 40 + lane] = v;
    }
}

// ---------------------------------------------------------------- launch
extern "C" void kernel_launch(void* const* d_in, const int* in_sizes, int n_in,
                              void* d_out, int out_size, void* d_ws, size_t ws_size,
                              hipStream_t stream) {
    const float* x           = (const float*)d_in[0];
    const float* edge_attr   = (const float*)d_in[1];
    const float* edge_weight = (const float*)d_in[2];
    const float* W0 = (const float*)d_in[4];
    const float* b0 = (const float*)d_in[5];
    const float* W  = (const float*)d_in[6];
    const float* b  = (const float*)d_in[7];
    const int* ei   = (const int*)d_in[8];

    float* out = (float*)d_out;
    float* h  = out;                          // output 0: [NN, HID]
    float* h0 = out + (size_t)NN * HID;       // output 1: [NN, HID]

    char* p = (char*)d_ws;
    auto alloc = [&](size_t bytes) { char* q = p; p += (bytes + 255) & ~(size_t)255; return q; };
    int*   rowptr  = (int*)  alloc((NN + 1) * sizeof(int));
    int*   cursor  = (int*)  alloc(NN * sizeof(int));
    int*   bsums   = (int*)  alloc(SCAN_B * sizeof(int));
    uint2* csr_sw  = (uint2*)alloc((size_t)NE * sizeof(uint2));
    uint2* csr_ew  = (uint2*)alloc((size_t)NE * sizeof(uint2));
    unsigned short* A1   = (unsigned short*)alloc((size_t)NN * KP1 * 2);
    unsigned short* h0b  = (unsigned short*)alloc((size_t)NN * NP * 2);
    unsigned short* aggB = (unsigned short*)alloc((size_t)NN * NP * 2);
    unsigned short* B0T  = (unsigned short*)alloc((size_t)NP * KP1 * 2);
    unsigned short* BT   = (unsigned short*)alloc((size_t)NP * KP2 * 2);

    hipMemsetAsync(rowptr, 0, (NN + 1) * sizeof(int), stream);
    hist_kernel<<<(NE + 255) / 256, 256, 0, stream>>>(ei, rowptr);
    scan1<<<SCAN_B, SCAN_T, 0, stream>>>(rowptr, bsums);
    scan2<<<1, SCAN_T, 0, stream>>>(bsums);
    scan3<<<SCAN_B, SCAN_T, 0, stream>>>(rowptr, bsums, cursor);
    fill_kernel<<<(NE + 255) / 256, 256, 0, stream>>>(ei, edge_weight, cursor,
                                                      csr_sw, csr_ew);
    castB0<<<NP, KP1, 0, stream>>>(W0, B0T);
    castB<<<NP, KP2, 0, stream>>>(W, BT);
    cast_x<<<(NN * 32 + 255) / 256, 256, 0, stream>>>(x, A1);
    inc_kernel<<<(NN + 3) / 4, 256, 0, stream>>>(edge_attr, rowptr, csr_ew, A1);

    // gemm1: 256 blocks (1/CU), full N=320 panel, 196 rows/block, 7 tiles
    gemm_stream<0, KP1, 320, 1, 4, 196><<<dim3(256, 1), 256, 0, stream>>>(
        A1, B0T, b0, nullptr, h0, h0b, NN);
    agg_kernel<<<(NN + 3) / 4, 256, 0, stream>>>(h0b, rowptr, csr_sw, aggB);
    // gemm2: 128x2 blocks (1/CU), N-half=160 panel, 391 rows/block, 13 tiles
    gemm_stream<1, KP2, 160, 2, 2, 391><<<dim3(128, 2), 256, 0, stream>>>(
        aggB, BT, b, h0, h, nullptr, NN);
}

// Round 5
// 456.398 us; speedup vs baseline: 1.2764x; 1.0367x over previous
//
#include <hip/hip_runtime.h>

#define NN 50000      // nodes
#define NE 800000     // edges
#define ND 128        // node_attr_dim
#define ED 16         // edge_attr_dim
#define HID 300       // hidden
#define KP1 192       // padded K for gemm1 (128+16 -> 192)
#define KP2 320       // padded K for gemm2 (300 -> 320)
#define NP 320        // padded N (300 -> 320)

#define SCAN_T 256
#define SCAN_B ((NN + SCAN_T - 1) / SCAN_T)   // 196 blocks

typedef __attribute__((ext_vector_type(8))) short short8;
typedef __attribute__((ext_vector_type(4))) float f32x4;

__device__ __forceinline__ unsigned short f2b(float f) {
    unsigned int u = __float_as_uint(f);
    u = (u + 0x7FFFu + ((u >> 16) & 1u)) >> 16;   // RNE
    return (unsigned short)u;
}
__device__ __forceinline__ float blo(unsigned int u) {
    return __uint_as_float(u << 16);
}
__device__ __forceinline__ float bhi(unsigned int u) {
    return __uint_as_float(u & 0xffff0000u);
}

// async global->LDS: 16B per lane, dest = wave-uniform base + lane*16
__device__ __forceinline__ void gload16(const void* g, void* l) {
    __builtin_amdgcn_global_load_lds(
        (const __attribute__((address_space(1))) void*)g,
        (__attribute__((address_space(3))) void*)l, 16, 0, 0);
}

// in-block inclusive scan of v across 256 threads (4 waves)
__device__ __forceinline__ int block_iscan(int v, int tid) {
    int lane = tid & 63;
    #pragma unroll
    for (int off = 1; off < 64; off <<= 1) {
        int t = __shfl_up(v, off);
        if (lane >= off) v += t;
    }
    __shared__ int wsum[4];
    int wid = tid >> 6;
    if (lane == 63) wsum[wid] = v;
    __syncthreads();
    int add = 0;
    #pragma unroll
    for (int w = 0; w < 4; ++w)
        if (w < wid) add += wsum[w];
    return v + add;
}

// ---------------------------------------------------------------- CSR build
__global__ void hist_kernel(const int* __restrict__ ei, int* __restrict__ rowptr) {
    int e = blockIdx.x * blockDim.x + threadIdx.x;
    if (e < NE) atomicAdd(&rowptr[ei[NE + e] + 1], 1);
}

// phase 1: local inclusive scan of rowptr[1..NN], block totals out
__global__ __launch_bounds__(SCAN_T) void scan1(int* __restrict__ rowptr,
                                                int* __restrict__ blockSums) {
    int i = blockIdx.x * SCAN_T + threadIdx.x;
    int v = (i < NN) ? rowptr[1 + i] : 0;
    v = block_iscan(v, threadIdx.x);
    if (i < NN) rowptr[1 + i] = v;
    if (threadIdx.x == SCAN_T - 1) blockSums[blockIdx.x] = v;
}

// phase 2: exclusive scan of block totals (196 <= 256, one block)
__global__ __launch_bounds__(SCAN_T) void scan2(int* __restrict__ blockSums) {
    int t = threadIdx.x;
    int orig = (t < SCAN_B) ? blockSums[t] : 0;
    int v = block_iscan(orig, t);
    if (t < SCAN_B) blockSums[t] = v - orig;   // exclusive
}

// phase 3: add block offsets; emit cursor[] (exclusive prefix per node)
__global__ __launch_bounds__(SCAN_T) void scan3(int* __restrict__ rowptr,
                                                const int* __restrict__ blockSums,
                                                int* __restrict__ cursor) {
    int i = blockIdx.x * SCAN_T + threadIdx.x;
    if (i < NN) {
        int v = rowptr[1 + i] + blockSums[blockIdx.x];
        rowptr[1 + i] = v;
        if (i + 1 < NN) cursor[i + 1] = v;
    }
    if (i == 0) cursor[0] = 0;
}

// packed CSR payloads: csr_sw = {src, w_bits}, csr_ew = {eid, w_bits}
__global__ void fill_kernel(const int* __restrict__ ei, const float* __restrict__ ew,
                            int* __restrict__ cursor, uint2* __restrict__ csr_sw,
                            uint2* __restrict__ csr_ew) {
    int e = blockIdx.x * blockDim.x + threadIdx.x;
    if (e < NE) {
        int d = ei[NE + e];
        int pos = atomicAdd(&cursor[d], 1);
        unsigned int wb = __float_as_uint(ew[e]);
        uint2 sw; sw.x = (unsigned int)ei[e]; sw.y = wb;
        uint2 ee; ee.x = (unsigned int)e;     ee.y = wb;
        csr_sw[pos] = sw;
        csr_ew[pos] = ee;
    }
}

// ------------------- cast x (fp32) -> A1 cols 0..127 (bf16), coalesced -----
__global__ __launch_bounds__(256) void cast_x(const float* __restrict__ x,
                                              unsigned short* __restrict__ A1) {
    int tid = blockIdx.x * blockDim.x + threadIdx.x;   // NN*32 threads
    if (tid >= NN * 32) return;
    int n = tid >> 5, q = tid & 31;
    float4 v = *(const float4*)&x[(size_t)n * ND + q * 4];
    unsigned short o[4] = {f2b(v.x), f2b(v.y), f2b(v.z), f2b(v.w)};
    *(uint2*)&A1[(size_t)n * KP1 + q * 4] = *(uint2*)o;
}

// ---- inc: wave per node; lanes = 4 edge-groups x 16 features; 2-deep MLP --
__global__ __launch_bounds__(256) void inc_kernel(
    const float* __restrict__ edge_attr,
    const int* __restrict__ rowptr,
    const uint2* __restrict__ csr_ew,
    unsigned short* __restrict__ A1) {
    int n = (blockIdx.x * blockDim.x + threadIdx.x) >> 6;
    int lane = threadIdx.x & 63;
    if (n >= NN) return;
    int g = lane >> 4, j = lane & 15;
    int lo = rowptr[n], hi = rowptr[n + 1];
    float v = 0.f;
    int k = lo + g;
    for (; k + 4 < hi; k += 8) {          // 2 edges per group in flight
        uint2 e0 = csr_ew[k], e1 = csr_ew[k + 4];
        float a0 = edge_attr[(size_t)e0.x * ED + j];
        float a1 = edge_attr[(size_t)e1.x * ED + j];
        v += __uint_as_float(e0.y) * a0;
        v += __uint_as_float(e1.y) * a1;
    }
    if (k < hi) {
        uint2 e0 = csr_ew[k];
        v += __uint_as_float(e0.y) * edge_attr[(size_t)e0.x * ED + j];
    }
    v += __shfl_xor(v, 16);
    v += __shfl_xor(v, 32);
    if (lane < 16)
        A1[(size_t)n * KP1 + ND + lane] = f2b(v);
    else
        A1[(size_t)n * KP1 + ND + lane] = 0;   // pad cols 144..191
}

// B0T[n][k] = bf16(W0[k][n]) padded to [320][192]
__global__ void castB0(const float* __restrict__ W0, unsigned short* __restrict__ B0T) {
    int n = blockIdx.x, k = threadIdx.x;
    float v = (n < HID && k < ND + ED) ? W0[(size_t)k * HID + n] : 0.f;
    B0T[(size_t)n * KP1 + k] = f2b(v);
}

// BT[n][k] = bf16(W[k][n]) padded to [320][320]
__global__ void castB(const float* __restrict__ W, unsigned short* __restrict__ BT) {
    int n = blockIdx.x, k = threadIdx.x;
    float v = (n < HID && k < HID) ? W[(size_t)k * HID + n] : 0.f;
    BT[(size_t)n * KP2 + k] = f2b(v);
}

// --------------------------------------------- persistent stream-M MFMA GEMM
// One block per CU. B panel staged in LDS ONCE (swizzled); A streamed in
// 32-row tiles, double-buffered via global_load_lds. Whole K-loop per tile
// runs barrier-free; one __syncthreads per tile whose vmcnt(0) drain is
// covered by ~2000cy of compute+epilogue. XOR swizzle both-sides (rule 21).
template <int MODE, int KP, int BN, int WM, int WN, int RPB>
__global__ __launch_bounds__(256) void gemm_stream(
    const unsigned short* __restrict__ A,   // [M, KP] bf16 row-major
    const unsigned short* __restrict__ BT,  // [320, KP] bf16 (B transposed)
    const float* __restrict__ bias,         // [300]
    const float* __restrict__ RES,          // MODE1: h0 [M,300] fp32
    float* __restrict__ C,                  // [M,300] fp32
    unsigned short* __restrict__ h0b,       // MODE0: [M,320] bf16
    int M)
{
    constexpr int CPR = KP / 8;          // 16B chunks per row
    constexpr int ACH = 32 * CPR;        // chunks per A buffer
    constexpr int BCH = BN * CPR;        // chunks in B panel
    constexpr int AM  = 32 / (16 * WM);  // a-frags per wave
    constexpr int BNW = BN / (16 * WN);  // b-frags per wave (=5)
    __shared__ unsigned short Bs[BCH * 8];     // g1:120KB g2:100KB
    __shared__ unsigned short As[2][ACH * 8];  // g1:24KB  g2:40KB

    const int tid = threadIdx.x;
    const int wave = tid >> 6, lane = tid & 63;
    const int wm = wave / WN, wn = wave % WN;
    const int quad = lane >> 4, lr = lane & 15;
    const int n00 = blockIdx.y * BN;
    const int rbase = blockIdx.x * RPB;
    const int rowend = min(rbase + RPB, M);
    const int nt = (rowend - rbase + 31) >> 5;

    // ---- stage B panel once (swizzled source, linear dest)
    #pragma unroll
    for (int rd = 0; rd < BCH / 256; ++rd) {
        int s = rd * 256 + tid;
        int row = s / CPR, c = s - row * CPR;
        int cs = (c & ~7) | ((c & 7) ^ (row & 7));
        gload16(&BT[(size_t)(n00 + row) * KP + cs * 8], &Bs[s * 8]);
    }
    auto stageA = [&](int buf, int mb) {
        #pragma unroll
        for (int rd = 0; rd < ACH / 256; ++rd) {
            int s = rd * 256 + tid;
            int row = s / CPR, c = s - row * CPR;
            int cs = (c & ~7) | ((c & 7) ^ (row & 7));
            int mg = mb + row; if (mg >= M) mg = M - 1;
            gload16(&A[(size_t)mg * KP + cs * 8], &As[buf][s * 8]);
        }
    };
    stageA(0, rbase);

    float bias_r[BNW];
    #pragma unroll
    for (int tn = 0; tn < BNW; ++tn) {
        int ng = n00 + wn * (BNW * 16) + tn * 16 + lr;
        bias_r[tn] = (ng < HID) ? bias[ng] : 0.f;
    }
    __syncthreads();   // drains vmcnt(0): B panel + first A tile resident

    int cur = 0;
    #pragma unroll 1
    for (int t = 0; t < nt; ++t) {
        const int mb = rbase + t * 32;
        if (t + 1 < nt) stageA(cur ^ 1, mb + 32);   // prefetch next tile

        float res_r[AM][BNW][4];
        if (MODE == 1) {   // prefetch residual before compute (latency hidden)
            #pragma unroll
            for (int tm = 0; tm < AM; ++tm)
            #pragma unroll
            for (int tn = 0; tn < BNW; ++tn) {
                int ng = n00 + wn * (BNW * 16) + tn * 16 + lr;
                int ngc = ng < HID ? ng : HID - 1;
                #pragma unroll
                for (int r = 0; r < 4; ++r) {
                    int mg = mb + (wm * AM + tm) * 16 + quad * 4 + r;
                    int mgc = mg < M ? mg : M - 1;
                    res_r[tm][tn][r] = RES[(size_t)mgc * HID + ngc];
                }
            }
        }

        f32x4 acc[AM][BNW] = {};
        const int rm = lr & 7;
        #pragma unroll
        for (int tt = 0; tt < KP / 32; ++tt) {
            int cA = tt * 4 + quad;
            int sw8 = ((cA & ~7) | ((cA & 7) ^ rm)) * 8;
            short8 a[AM], b[BNW];
            #pragma unroll
            for (int tm = 0; tm < AM; ++tm) {
                int ar = (wm * AM + tm) * 16 + lr;
                a[tm] = *(const short8*)&As[cur][ar * KP + sw8];
            }
            #pragma unroll
            for (int tn = 0; tn < BNW; ++tn) {
                int br = wn * (BNW * 16) + tn * 16 + lr;
                b[tn] = *(const short8*)&Bs[br * KP + sw8];
            }
            #pragma unroll
            for (int tm = 0; tm < AM; ++tm)
                #pragma unroll
                for (int tn = 0; tn < BNW; ++tn)
                    acc[tm][tn] = __builtin_amdgcn_mfma_f32_16x16x32_bf16(
                        a[tm], b[tn], acc[tm][tn], 0, 0, 0);
        }

        #pragma unroll
        for (int tm = 0; tm < AM; ++tm)
        #pragma unroll
        for (int tn = 0; tn < BNW; ++tn) {
            int ng = n00 + wn * (BNW * 16) + tn * 16 + lr;
            #pragma unroll
            for (int r = 0; r < 4; ++r) {
                int mg = mb + (wm * AM + tm) * 16 + quad * 4 + r;
                if (mg < rowend && ng < HID) {
                    float v = acc[tm][tn][r] + bias_r[tn];
                    if (MODE == 1) v += res_r[tm][tn][r];
                    v = fmaxf(v, 0.f);
                    C[(size_t)mg * HID + ng] = v;
                    if (MODE == 0) h0b[(size_t)mg * NP + ng] = f2b(v);
                }
            }
        }
        __syncthreads();   // next-tile stage (issued pre-compute) now drained
        cur ^= 1;
    }
}

// ---------------- aggB[n] = bf16(mean_k w_k * h0b[src_k]) ------------------
__device__ __forceinline__ void acc8(float* acc, float w, const uint4& r) {
    acc[0] += w * blo(r.x); acc[1] += w * bhi(r.x);
    acc[2] += w * blo(r.y); acc[3] += w * bhi(r.y);
    acc[4] += w * blo(r.z); acc[5] += w * bhi(r.z);
    acc[6] += w * blo(r.w); acc[7] += w * bhi(r.w);
}

// wave per node; 40 lanes x 16B cover the 640B row; FOUR gathered rows in
// flight per iteration (latency-bound gather -> deepen MLP).
__global__ __launch_bounds__(256) void agg_kernel(
    const unsigned short* __restrict__ h0b,   // [NN, 320] bf16
    const int* __restrict__ rowptr,
    const uint2* __restrict__ csr_sw,
    unsigned short* __restrict__ aggB)        // [NN, 320] bf16, pad cols = 0
{
    int n = (blockIdx.x * blockDim.x + threadIdx.x) >> 6;
    int lane = threadIdx.x & 63;
    if (n >= NN) return;
    int lo = rowptr[n], hi = rowptr[n + 1];
    float acc[8] = {};
    const uint4* h4 = (const uint4*)h0b;      // row stride = 40 uint4
    bool act = lane < 40;
    int k = lo;
    for (; k + 3 < hi; k += 4) {
        uint2 p0 = csr_sw[k],     p1 = csr_sw[k + 1];
        uint2 p2 = csr_sw[k + 2], p3 = csr_sw[k + 3];
        uint4 r0 = {0,0,0,0}, r1 = {0,0,0,0}, r2 = {0,0,0,0}, r3 = {0,0,0,0};
        if (act) {
            r0 = h4[(size_t)p0.x * 40 + lane];
            r1 = h4[(size_t)p1.x * 40 + lane];
            r2 = h4[(size_t)p2.x * 40 + lane];
            r3 = h4[(size_t)p3.x * 40 + lane];
        }
        acc8(acc, __uint_as_float(p0.y), r0);
        acc8(acc, __uint_as_float(p1.y), r1);
        acc8(acc, __uint_as_float(p2.y), r2);
        acc8(acc, __uint_as_float(p3.y), r3);
    }
    for (; k < hi; ++k) {
        uint2 p0 = csr_sw[k];
        uint4 r0 = {0,0,0,0};
        if (act) r0 = h4[(size_t)p0.x * 40 + lane];
        acc8(acc, __uint_as_float(p0.y), r0);
    }
    if (act) {
        float invd = 1.f / fmaxf((float)(hi - lo), 1.f);
        int cbase = lane * 8;
        unsigned int o[4];
        #pragma unroll
        for (int i = 0; i < 4; ++i) {
            int c0 = cbase + 2 * i, c1 = c0 + 1;
            unsigned int ulo = (c0 < HID) ? f2b(acc[2 * i] * invd) : 0;
            unsigned int uhi = (c1 < HID) ? f2b(acc[2 * i + 1] * invd) : 0;
            o[i] = ulo | (uhi << 16);
        }
        uint4* a4 = (uint4*)aggB;
        uint4 v; v.x = o[0]; v.y = o[1]; v.z = o[2]; v.w = o[3];
        a4[(size_t)n * 40 + lane] = v;
    }
}

// ---------------------------------------------------------------- launch
extern "C" void kernel_launch(void* const* d_in, const int* in_sizes, int n_in,
                              void* d_out, int out_size, void* d_ws, size_t ws_size,
                              hipStream_t stream) {
    const float* x           = (const float*)d_in[0];
    const float* edge_attr   = (const float*)d_in[1];
    const float* edge_weight = (const float*)d_in[2];
    const float* W0 = (const float*)d_in[4];
    const float* b0 = (const float*)d_in[5];
    const float* W  = (const float*)d_in[6];
    const float* b  = (const float*)d_in[7];
    const int* ei   = (const int*)d_in[8];

    float* out = (float*)d_out;
    float* h  = out;                          // output 0: [NN, HID]
    float* h0 = out + (size_t)NN * HID;       // output 1: [NN, HID]

    char* p = (char*)d_ws;
    auto alloc = [&](size_t bytes) { char* q = p; p += (bytes + 255) & ~(size_t)255; return q; };
    int*   rowptr  = (int*)  alloc((NN + 1) * sizeof(int));
    int*   cursor  = (int*)  alloc(NN * sizeof(int));
    int*   bsums   = (int*)  alloc(SCAN_B * sizeof(int));
    uint2* csr_sw  = (uint2*)alloc((size_t)NE * sizeof(uint2));
    uint2* csr_ew  = (uint2*)alloc((size_t)NE * sizeof(uint2));
    unsigned short* A1   = (unsigned short*)alloc((size_t)NN * KP1 * 2);
    unsigned short* h0b  = (unsigned short*)alloc((size_t)NN * NP * 2);
    unsigned short* aggB = (unsigned short*)alloc((size_t)NN * NP * 2);
    unsigned short* B0T  = (unsigned short*)alloc((size_t)NP * KP1 * 2);
    unsigned short* BT   = (unsigned short*)alloc((size_t)NP * KP2 * 2);

    hipMemsetAsync(rowptr, 0, (NN + 1) * sizeof(int), stream);
    hist_kernel<<<(NE + 255) / 256, 256, 0, stream>>>(ei, rowptr);
    scan1<<<SCAN_B, SCAN_T, 0, stream>>>(rowptr, bsums);
    scan2<<<1, SCAN_T, 0, stream>>>(bsums);
    scan3<<<SCAN_B, SCAN_T, 0, stream>>>(rowptr, bsums, cursor);
    fill_kernel<<<(NE + 255) / 256, 256, 0, stream>>>(ei, edge_weight, cursor,
                                                      csr_sw, csr_ew);
    castB0<<<NP, KP1, 0, stream>>>(W0, B0T);
    castB<<<NP, KP2, 0, stream>>>(W, BT);
    cast_x<<<(NN * 32 + 255) / 256, 256, 0, stream>>>(x, A1);
    inc_kernel<<<(NN + 3) / 4, 256, 0, stream>>>(edge_attr, rowptr, csr_ew, A1);

    // gemm1: 256 blocks (1/CU), full N=320 panel, 196 rows/block, 7 tiles
    gemm_stream<0, KP1, 320, 1, 4, 196><<<dim3(256, 1), 256, 0, stream>>>(
        A1, B0T, b0, nullptr, h0, h0b, NN);
    agg_kernel<<<(NN + 3) / 4, 256, 0, stream>>>(h0b, rowptr, csr_sw, aggB);
    // gemm2: 128x2 blocks (1/CU), N-half=160 panel, 391 rows/block, 13 tiles
    gemm_stream<1, KP2, 160, 2, 2, 391><<<dim3(128, 2), 256, 0, stream>>>(
        aggB, BT, b, h0, h, nullptr, NN);
}

// Round 6
// 447.152 us; speedup vs baseline: 1.3027x; 1.0207x over previous
//
#include <hip/hip_runtime.h>

#define NN 50000      // nodes
#define NE 800000     // edges
#define ND 128        // node_attr_dim
#define ED 16         // edge_attr_dim
#define HID 300       // hidden
#define KP1 192       // padded K for gemm1 (128+16 -> 192)
#define KP2 320       // padded K for gemm2 (300 -> 320)
#define NP 320        // padded N (300 -> 320)

#define SCAN_T 256
#define SCAN_B ((NN + SCAN_T - 1) / SCAN_T)   // 196 blocks

typedef __attribute__((ext_vector_type(8))) short short8;
typedef __attribute__((ext_vector_type(4))) float f32x4;

__device__ __forceinline__ unsigned short f2b(float f) {
    unsigned int u = __float_as_uint(f);
    u = (u + 0x7FFFu + ((u >> 16) & 1u)) >> 16;   // RNE
    return (unsigned short)u;
}
__device__ __forceinline__ float blo(unsigned int u) {
    return __uint_as_float(u << 16);
}
__device__ __forceinline__ float bhi(unsigned int u) {
    return __uint_as_float(u & 0xffff0000u);
}

// async global->LDS: 16B per lane, dest = wave-uniform base + lane*16
__device__ __forceinline__ void gload16(const void* g, void* l) {
    __builtin_amdgcn_global_load_lds(
        (const __attribute__((address_space(1))) void*)g,
        (__attribute__((address_space(3))) void*)l, 16, 0, 0);
}

// in-block inclusive scan of v across 256 threads (4 waves)
__device__ __forceinline__ int block_iscan(int v, int tid) {
    int lane = tid & 63;
    #pragma unroll
    for (int off = 1; off < 64; off <<= 1) {
        int t = __shfl_up(v, off);
        if (lane >= off) v += t;
    }
    __shared__ int wsum[4];
    int wid = tid >> 6;
    if (lane == 63) wsum[wid] = v;
    __syncthreads();
    int add = 0;
    #pragma unroll
    for (int w = 0; w < 4; ++w)
        if (w < wid) add += wsum[w];
    return v + add;
}

// ---------------------------------------------------------------- CSR build
__global__ void hist_kernel(const int* __restrict__ ei, int* __restrict__ rowptr) {
    int e = blockIdx.x * blockDim.x + threadIdx.x;
    if (e < NE) atomicAdd(&rowptr[ei[NE + e] + 1], 1);
}

// phase 1: local inclusive scan of rowptr[1..NN], block totals out
__global__ __launch_bounds__(SCAN_T) void scan1(int* __restrict__ rowptr,
                                                int* __restrict__ blockSums) {
    int i = blockIdx.x * SCAN_T + threadIdx.x;
    int v = (i < NN) ? rowptr[1 + i] : 0;
    v = block_iscan(v, threadIdx.x);
    if (i < NN) rowptr[1 + i] = v;
    if (threadIdx.x == SCAN_T - 1) blockSums[blockIdx.x] = v;
}

// phase 2: exclusive scan of block totals (196 <= 256, one block)
__global__ __launch_bounds__(SCAN_T) void scan2(int* __restrict__ blockSums) {
    int t = threadIdx.x;
    int orig = (t < SCAN_B) ? blockSums[t] : 0;
    int v = block_iscan(orig, t);
    if (t < SCAN_B) blockSums[t] = v - orig;   // exclusive
}

// phase 3: add block offsets; emit cursor[] (exclusive prefix per node)
__global__ __launch_bounds__(SCAN_T) void scan3(int* __restrict__ rowptr,
                                                const int* __restrict__ blockSums,
                                                int* __restrict__ cursor) {
    int i = blockIdx.x * SCAN_T + threadIdx.x;
    if (i < NN) {
        int v = rowptr[1 + i] + blockSums[blockIdx.x];
        rowptr[1 + i] = v;
        if (i + 1 < NN) cursor[i + 1] = v;
    }
    if (i == 0) cursor[0] = 0;
}

// single packed CSR payload: csr[pos] = {src, eid, w_bits, 0}
// ONE 16B random scatter per edge (was two 8B scatters to two arrays ->
// halves the randomly-touched L2 lines in the RMW path).
__global__ void fill_kernel(const int* __restrict__ ei, const float* __restrict__ ew,
                            int* __restrict__ cursor, uint4* __restrict__ csr) {
    int e = blockIdx.x * blockDim.x + threadIdx.x;
    if (e < NE) {
        int d = ei[NE + e];
        int pos = atomicAdd(&cursor[d], 1);
        uint4 q;
        q.x = (unsigned int)ei[e];
        q.y = (unsigned int)e;
        q.z = __float_as_uint(ew[e]);
        q.w = 0;
        csr[pos] = q;
    }
}

// ---- prep: fused cast_x + inc. Wave per node.
// Phase A: cast x row (64 lanes x float2 = 512B) -> A1 cols 0..127.
// Phase B: inc gather, 4 groups x 16 feature-lanes, 2-deep MLP with
// clamped-index predication (no serial tail).
__global__ __launch_bounds__(256) void prep_kernel(
    const float* __restrict__ x,
    const float* __restrict__ edge_attr,
    const int* __restrict__ rowptr,
    const uint4* __restrict__ csr,
    unsigned short* __restrict__ A1) {
    int n = (blockIdx.x * blockDim.x + threadIdx.x) >> 6;
    int lane = threadIdx.x & 63;
    if (n >= NN) return;

    float2 v = *(const float2*)&x[(size_t)n * ND + lane * 2];
    unsigned int o = (unsigned int)f2b(v.x) | ((unsigned int)f2b(v.y) << 16);
    *(unsigned int*)&A1[(size_t)n * KP1 + lane * 2] = o;

    int g = lane >> 4, j = lane & 15;
    int lo = rowptr[n], hi = rowptr[n + 1];
    float s = 0.f;
    for (int k = lo + g; k < hi; k += 8) {        // 2 edges per group in flight
        int k1 = (k + 4 < hi) ? k + 4 : k;        // clamp: always valid
        uint4 e0 = csr[k];
        uint4 e1 = csr[k1];
        float a0 = edge_attr[(size_t)e0.y * ED + j];
        float a1 = edge_attr[(size_t)e1.y * ED + j];
        s += __uint_as_float(e0.z) * a0;
        s += ((k + 4 < hi) ? __uint_as_float(e1.z) : 0.f) * a1;
    }
    s += __shfl_xor(s, 16);
    s += __shfl_xor(s, 32);
    if (lane < 16)
        A1[(size_t)n * KP1 + ND + lane] = f2b(s);
    else
        A1[(size_t)n * KP1 + ND + lane] = 0;      // pad cols 144..191
}

// B0T[n][k] = bf16(W0[k][n]) padded to [320][192]
__global__ void castB0(const float* __restrict__ W0, unsigned short* __restrict__ B0T) {
    int n = blockIdx.x, k = threadIdx.x;
    float v = (n < HID && k < ND + ED) ? W0[(size_t)k * HID + n] : 0.f;
    B0T[(size_t)n * KP1 + k] = f2b(v);
}

// BT[n][k] = bf16(W[k][n]) padded to [320][320]
__global__ void castB(const float* __restrict__ W, unsigned short* __restrict__ BT) {
    int n = blockIdx.x, k = threadIdx.x;
    float v = (n < HID && k < HID) ? W[(size_t)k * HID + n] : 0.f;
    BT[(size_t)n * KP2 + k] = f2b(v);
}

// --------------------------------------------- persistent stream-M MFMA GEMM
// One block per CU. B panel staged in LDS ONCE (swizzled); A streamed in
// 32-row tiles, double-buffered via global_load_lds. Whole K-loop per tile
// runs barrier-free; one __syncthreads per tile whose vmcnt(0) drain is
// covered by ~2000cy of compute+epilogue. XOR swizzle both-sides (rule 21).
template <int MODE, int KP, int BN, int WM, int WN, int RPB>
__global__ __launch_bounds__(256) void gemm_stream(
    const unsigned short* __restrict__ A,   // [M, KP] bf16 row-major
    const unsigned short* __restrict__ BT,  // [320, KP] bf16 (B transposed)
    const float* __restrict__ bias,         // [300]
    const float* __restrict__ RES,          // MODE1: h0 [M,300] fp32
    float* __restrict__ C,                  // [M,300] fp32
    unsigned short* __restrict__ h0b,       // MODE0: [M,320] bf16
    int M)
{
    constexpr int CPR = KP / 8;          // 16B chunks per row
    constexpr int ACH = 32 * CPR;        // chunks per A buffer
    constexpr int BCH = BN * CPR;        // chunks in B panel
    constexpr int AM  = 32 / (16 * WM);  // a-frags per wave
    constexpr int BNW = BN / (16 * WN);  // b-frags per wave (=5)
    __shared__ unsigned short Bs[BCH * 8];     // g1:120KB g2:100KB
    __shared__ unsigned short As[2][ACH * 8];  // g1:24KB  g2:40KB

    const int tid = threadIdx.x;
    const int wave = tid >> 6, lane = tid & 63;
    const int wm = wave / WN, wn = wave % WN;
    const int quad = lane >> 4, lr = lane & 15;
    const int n00 = blockIdx.y * BN;
    const int rbase = blockIdx.x * RPB;
    const int rowend = min(rbase + RPB, M);
    const int nt = (rowend - rbase + 31) >> 5;

    // ---- stage B panel once (swizzled source, linear dest)
    #pragma unroll
    for (int rd = 0; rd < BCH / 256; ++rd) {
        int s = rd * 256 + tid;
        int row = s / CPR, c = s - row * CPR;
        int cs = (c & ~7) | ((c & 7) ^ (row & 7));
        gload16(&BT[(size_t)(n00 + row) * KP + cs * 8], &Bs[s * 8]);
    }
    auto stageA = [&](int buf, int mb) {
        #pragma unroll
        for (int rd = 0; rd < ACH / 256; ++rd) {
            int s = rd * 256 + tid;
            int row = s / CPR, c = s - row * CPR;
            int cs = (c & ~7) | ((c & 7) ^ (row & 7));
            int mg = mb + row; if (mg >= M) mg = M - 1;
            gload16(&A[(size_t)mg * KP + cs * 8], &As[buf][s * 8]);
        }
    };
    stageA(0, rbase);

    float bias_r[BNW];
    #pragma unroll
    for (int tn = 0; tn < BNW; ++tn) {
        int ng = n00 + wn * (BNW * 16) + tn * 16 + lr;
        bias_r[tn] = (ng < HID) ? bias[ng] : 0.f;
    }
    __syncthreads();   // drains vmcnt(0): B panel + first A tile resident

    int cur = 0;
    #pragma unroll 1
    for (int t = 0; t < nt; ++t) {
        const int mb = rbase + t * 32;
        if (t + 1 < nt) stageA(cur ^ 1, mb + 32);   // prefetch next tile

        float res_r[AM][BNW][4];
        if (MODE == 1) {   // prefetch residual before compute (latency hidden)
            #pragma unroll
            for (int tm = 0; tm < AM; ++tm)
            #pragma unroll
            for (int tn = 0; tn < BNW; ++tn) {
                int ng = n00 + wn * (BNW * 16) + tn * 16 + lr;
                int ngc = ng < HID ? ng : HID - 1;
                #pragma unroll
                for (int r = 0; r < 4; ++r) {
                    int mg = mb + (wm * AM + tm) * 16 + quad * 4 + r;
                    int mgc = mg < M ? mg : M - 1;
                    res_r[tm][tn][r] = RES[(size_t)mgc * HID + ngc];
                }
            }
        }

        f32x4 acc[AM][BNW] = {};
        const int rm = lr & 7;
        #pragma unroll
        for (int tt = 0; tt < KP / 32; ++tt) {
            int cA = tt * 4 + quad;
            int sw8 = ((cA & ~7) | ((cA & 7) ^ rm)) * 8;
            short8 a[AM], b[BNW];
            #pragma unroll
            for (int tm = 0; tm < AM; ++tm) {
                int ar = (wm * AM + tm) * 16 + lr;
                a[tm] = *(const short8*)&As[cur][ar * KP + sw8];
            }
            #pragma unroll
            for (int tn = 0; tn < BNW; ++tn) {
                int br = wn * (BNW * 16) + tn * 16 + lr;
                b[tn] = *(const short8*)&Bs[br * KP + sw8];
            }
            #pragma unroll
            for (int tm = 0; tm < AM; ++tm)
                #pragma unroll
                for (int tn = 0; tn < BNW; ++tn)
                    acc[tm][tn] = __builtin_amdgcn_mfma_f32_16x16x32_bf16(
                        a[tm], b[tn], acc[tm][tn], 0, 0, 0);
        }

        #pragma unroll
        for (int tm = 0; tm < AM; ++tm)
        #pragma unroll
        for (int tn = 0; tn < BNW; ++tn) {
            int ng = n00 + wn * (BNW * 16) + tn * 16 + lr;
            #pragma unroll
            for (int r = 0; r < 4; ++r) {
                int mg = mb + (wm * AM + tm) * 16 + quad * 4 + r;
                if (mg < rowend && ng < HID) {
                    float v = acc[tm][tn][r] + bias_r[tn];
                    if (MODE == 1) v += res_r[tm][tn][r];
                    v = fmaxf(v, 0.f);
                    C[(size_t)mg * HID + ng] = v;
                    if (MODE == 0) h0b[(size_t)mg * NP + ng] = f2b(v);
                }
            }
        }
        __syncthreads();   // next-tile stage (issued pre-compute) now drained
        cur ^= 1;
    }
}

// ---------------- aggB[n] = bf16(mean_k w_k * h0b[src_k]) ------------------
__device__ __forceinline__ void acc8(float* acc, float w, const uint4& r) {
    acc[0] += w * blo(r.x); acc[1] += w * bhi(r.x);
    acc[2] += w * blo(r.y); acc[3] += w * bhi(r.y);
    acc[4] += w * blo(r.z); acc[5] += w * bhi(r.z);
    acc[6] += w * blo(r.w); acc[7] += w * bhi(r.w);
}

// wave per node; 40 lanes x 16B cover the 640B row; FOUR gathered rows in
// flight, clamped-index predication removes the serial tail entirely.
__global__ __launch_bounds__(256) void agg_kernel(
    const unsigned short* __restrict__ h0b,   // [NN, 320] bf16
    const int* __restrict__ rowptr,
    const uint4* __restrict__ csr,
    unsigned short* __restrict__ aggB)        // [NN, 320] bf16, pad cols = 0
{
    int n = (blockIdx.x * blockDim.x + threadIdx.x) >> 6;
    int lane = threadIdx.x & 63;
    if (n >= NN) return;
    int lo = rowptr[n], hi = rowptr[n + 1];
    float acc[8] = {};
    const uint4* h4 = (const uint4*)h0b;      // row stride = 40 uint4
    bool act = lane < 40;
    for (int k = lo; k < hi; k += 4) {        // 4-deep, clamp-predicated
        int k1 = (k + 1 < hi) ? k + 1 : k;
        int k2 = (k + 2 < hi) ? k + 2 : k;
        int k3 = (k + 3 < hi) ? k + 3 : k;
        uint4 p0 = csr[k], p1 = csr[k1], p2 = csr[k2], p3 = csr[k3];
        float w0 = __uint_as_float(p0.z);
        float w1 = (k + 1 < hi) ? __uint_as_float(p1.z) : 0.f;
        float w2 = (k + 2 < hi) ? __uint_as_float(p2.z) : 0.f;
        float w3 = (k + 3 < hi) ? __uint_as_float(p3.z) : 0.f;
        uint4 r0 = {0,0,0,0}, r1 = {0,0,0,0}, r2 = {0,0,0,0}, r3 = {0,0,0,0};
        if (act) {
            r0 = h4[(size_t)p0.x * 40 + lane];
            r1 = h4[(size_t)p1.x * 40 + lane];
            r2 = h4[(size_t)p2.x * 40 + lane];
            r3 = h4[(size_t)p3.x * 40 + lane];
        }
        acc8(acc, w0, r0);
        acc8(acc, w1, r1);
        acc8(acc, w2, r2);
        acc8(acc, w3, r3);
    }
    if (act) {
        float invd = 1.f / fmaxf((float)(hi - lo), 1.f);
        int cbase = lane * 8;
        unsigned int o[4];
        #pragma unroll
        for (int i = 0; i < 4; ++i) {
            int c0 = cbase + 2 * i, c1 = c0 + 1;
            unsigned int ulo = (c0 < HID) ? f2b(acc[2 * i] * invd) : 0;
            unsigned int uhi = (c1 < HID) ? f2b(acc[2 * i + 1] * invd) : 0;
            o[i] = ulo | (uhi << 16);
        }
        uint4* a4 = (uint4*)aggB;
        uint4 v; v.x = o[0]; v.y = o[1]; v.z = o[2]; v.w = o[3];
        a4[(size_t)n * 40 + lane] = v;
    }
}

// ---------------------------------------------------------------- launch
extern "C" void kernel_launch(void* const* d_in, const int* in_sizes, int n_in,
                              void* d_out, int out_size, void* d_ws, size_t ws_size,
                              hipStream_t stream) {
    const float* x           = (const float*)d_in[0];
    const float* edge_attr   = (const float*)d_in[1];
    const float* edge_weight = (const float*)d_in[2];
    const float* W0 = (const float*)d_in[4];
    const float* b0 = (const float*)d_in[5];
    const float* W  = (const float*)d_in[6];
    const float* b  = (const float*)d_in[7];
    const int* ei   = (const int*)d_in[8];

    float* out = (float*)d_out;
    float* h  = out;                          // output 0: [NN, HID]
    float* h0 = out + (size_t)NN * HID;       // output 1: [NN, HID]

    char* p = (char*)d_ws;
    auto alloc = [&](size_t bytes) { char* q = p; p += (bytes + 255) & ~(size_t)255; return q; };
    int*   rowptr  = (int*)  alloc((NN + 1) * sizeof(int));
    int*   cursor  = (int*)  alloc(NN * sizeof(int));
    int*   bsums   = (int*)  alloc(SCAN_B * sizeof(int));
    uint4* csr     = (uint4*)alloc((size_t)NE * sizeof(uint4));
    unsigned short* A1   = (unsigned short*)alloc((size_t)NN * KP1 * 2);
    unsigned short* h0b  = (unsigned short*)alloc((size_t)NN * NP * 2);
    unsigned short* aggB = (unsigned short*)alloc((size_t)NN * NP * 2);
    unsigned short* B0T  = (unsigned short*)alloc((size_t)NP * KP1 * 2);
    unsigned short* BT   = (unsigned short*)alloc((size_t)NP * KP2 * 2);

    hipMemsetAsync(rowptr, 0, (NN + 1) * sizeof(int), stream);
    hist_kernel<<<(NE + 255) / 256, 256, 0, stream>>>(ei, rowptr);
    scan1<<<SCAN_B, SCAN_T, 0, stream>>>(rowptr, bsums);
    scan2<<<1, SCAN_T, 0, stream>>>(bsums);
    scan3<<<SCAN_B, SCAN_T, 0, stream>>>(rowptr, bsums, cursor);
    fill_kernel<<<(NE + 255) / 256, 256, 0, stream>>>(ei, edge_weight, cursor, csr);
    castB0<<<NP, KP1, 0, stream>>>(W0, B0T);
    castB<<<NP, KP2, 0, stream>>>(W, BT);
    prep_kernel<<<(NN + 3) / 4, 256, 0, stream>>>(x, edge_attr, rowptr, csr, A1);

    // gemm1: 256 blocks (1/CU), full N=320 panel, 196 rows/block, 7 tiles
    gemm_stream<0, KP1, 320, 1, 4, 196><<<dim3(256, 1), 256, 0, stream>>>(
        A1, B0T, b0, nullptr, h0, h0b, NN);
    agg_kernel<<<(NN + 3) / 4, 256, 0, stream>>>(h0b, rowptr, csr, aggB);
    // gemm2: 128x2 blocks (1/CU), N-half=160 panel, 391 rows/block, 13 tiles
    gemm_stream<1, KP2, 160, 2, 2, 391><<<dim3(128, 2), 256, 0, stream>>>(
        aggB, BT, b, h0, h, nullptr, NN);
}